// Round 2
// baseline (976.583 us; speedup 1.0000x reference)
//
#include <hip/hip_runtime.h>
#include <hip/hip_cooperative_groups.h>
#include <math.h>

namespace cg = cooperative_groups;

#define HID 1024
#define VOC 50257
#define MLEN 12
#define NB 1024
#define NT 256

// mega ws layout (floats)
#define WS_ATTN   0      // [1024] attn_applied
#define WS_X      1024   // [1024] relu output
#define WS_PCOMB  2048   // [1024] comb_W[:, :H] @ embedded + comb_b
#define WS_HH     3072   // [4096] W_hh @ h0 + b_ih + b_hh
#define WS_GATES  7168   // [4096]
#define WS_H      11264  // [1024] h_new (16B aligned)
#define WS_PART   12288  // [2*NB] per-block (m, s) LSE partials

__device__ __forceinline__ float wave_reduce_sum(float v) {
    for (int off = 32; off > 0; off >>= 1)
        v += __shfl_down(v, off, 64);
    return v;
}

__device__ __forceinline__ void merge_ms(float& m, float& s, float m2, float s2) {
    float M = fmaxf(m, m2);
    s = s * expf(m - M) + s2 * expf(m2 - M);
    m = M;
}

__global__ __launch_bounds__(NT, 4) void mega(
    const int* __restrict__ tok_p, const float* __restrict__ h0,
    const float* __restrict__ enc, const float* __restrict__ emb,
    const float* __restrict__ attn_W, const float* __restrict__ attn_b,
    const float* __restrict__ comb_W, const float* __restrict__ comb_b,
    const float* __restrict__ W_ih, const float* __restrict__ W_hh,
    const float* __restrict__ b_ih, const float* __restrict__ b_hh,
    const float* __restrict__ out_W, const float* __restrict__ out_b,
    const float* __restrict__ c0, float* __restrict__ ws,
    float* __restrict__ out_logp, float* __restrict__ out_h,
    float* __restrict__ out_c, float* __restrict__ out_attnw)
{
    cg::grid_group grid = cg::this_grid();
    const int t = threadIdx.x;
    const int wid = t >> 6, lane = t & 63;
    const int bid = blockIdx.x;
    __shared__ float lds_w[MLEN];
    __shared__ float lds_m[4], lds_s[4];
    __shared__ float lds_bcast;

    const int tok = tok_p[0];  // int64 low word (tok < 50257)
    const float4* emb4 = (const float4*)(emb + (size_t)tok * HID);
    const float4* h04  = (const float4*)h0;

    // ---- Phase A: attention (block 0) + input-only GEMVs (blocks 1..1023) ----
    if (bid == 0) {
        __shared__ float lds_logits[MLEN];
        const float4* aW4 = (const float4*)attn_W;
        for (int l = wid; l < MLEN; l += 4) {
            float s = 0.f;
            for (int k = 0; k < 8; ++k) {
                int idx = k * 64 + lane;                    // 0..511 float4s of [emb,h0]
                float4 v = (idx < 256) ? emb4[idx] : h04[idx - 256];
                float4 w = aW4[l * 512 + idx];
                s += v.x * w.x + v.y * w.y + v.z * w.z + v.w * w.w;
            }
            s = wave_reduce_sum(s);
            if (lane == 0) lds_logits[l] = s + attn_b[l];
        }
        __syncthreads();
        if (t == 0) {
            float m = -1e30f;
            for (int l = 0; l < MLEN; ++l) m = fmaxf(m, lds_logits[l]);
            float ssum = 0.f;
            for (int l = 0; l < MLEN; ++l) { float e = expf(lds_logits[l] - m); lds_w[l] = e; ssum += e; }
            float inv = 1.f / ssum;
            for (int l = 0; l < MLEN; ++l) { lds_w[l] *= inv; out_attnw[l] = lds_w[l]; }
        }
        __syncthreads();
        const float4* enc4 = (const float4*)enc;
        float4 acc = make_float4(0.f, 0.f, 0.f, 0.f);
        for (int l = 0; l < MLEN; ++l) {
            float wl = lds_w[l];
            float4 v = enc4[l * 256 + t];
            acc.x += wl * v.x; acc.y += wl * v.y; acc.z += wl * v.z; acc.w += wl * v.w;
        }
        ((float4*)(ws + WS_ATTN))[t] = acc;
    } else {
        const int gid = (bid - 1) * 4 + wid;                // 0..4091
        for (int task = gid; task < 5120; task += 4092) {
            float s = 0.f;
            if (task < 1024) {
                // pcomb[task] = comb_W[task, :H] @ embedded + comb_b[task]
                const float4* W4 = (const float4*)(comb_W + (size_t)task * 2 * HID);
                for (int k = 0; k < 4; ++k) {
                    int idx = k * 64 + lane;
                    float4 w = W4[idx], v = emb4[idx];
                    s += w.x * v.x + w.y * v.y + w.z * v.z + w.w * v.w;
                }
                s = wave_reduce_sum(s);
                if (lane == 0) ws[WS_PCOMB + task] = s + comb_b[task];
            } else {
                // hh[r] = W_hh[r,:] @ h0 + b_ih[r] + b_hh[r]
                const int r = task - 1024;                  // 0..4095
                const float4* W4 = (const float4*)(W_hh + (size_t)r * HID);
                for (int k = 0; k < 4; ++k) {
                    int idx = k * 64 + lane;
                    float4 w = W4[idx], v = h04[idx];
                    s += w.x * v.x + w.y * v.y + w.z * v.z + w.w * v.w;
                }
                s = wave_reduce_sum(s);
                if (lane == 0) ws[WS_HH + r] = s + b_ih[r] + b_hh[r];
            }
        }
    }
    grid.sync();

    // ---- Phase B: x = relu(pcomb + comb_W[:, H:] @ attn); prefetch out_W [0,8MB) ----
    {
        const int gid = bid * 4 + wid;
        if (gid < 1024) {
            const float4* W4 = (const float4*)(comb_W + (size_t)gid * 2 * HID + HID);
            const float4* v4 = (const float4*)(ws + WS_ATTN);
            float s = 0.f;
            for (int k = 0; k < 4; ++k) {
                int idx = k * 64 + lane;
                float4 w = W4[idx], v = v4[idx];
                s += w.x * v.x + w.y * v.y + w.z * v.z + w.w * v.w;
            }
            s = wave_reduce_sum(s);
            if (lane == 0) ws[WS_X + gid] = fmaxf(s + ws[WS_PCOMB + gid], 0.f);
        } else if (bid >= 256 && bid < 512) {
            const int p = bid - 256;                        // 0..255, 32KB each
            const float4* W4 = (const float4*)out_W;
            float acc = 0.f;
            for (int i = 0; i < 8; ++i) {
                float4 v = W4[(size_t)p * 2048 + i * 256 + t];
                acc += v.x + v.y + v.z + v.w;
            }
            asm volatile("" :: "v"(acc));                   // keep loads live
        }
    }
    grid.sync();

    // ---- Phase C: gates[r] = hh[r] + W_ih[r,:] @ x (BW-saturated, no prefetch) ----
    {
        const int r = bid * 4 + wid;                        // 0..4095
        const float4* W4 = (const float4*)(W_ih + (size_t)r * HID);
        const float4* x4 = (const float4*)(ws + WS_X);
        float s = 0.f;
        for (int k = 0; k < 4; ++k) {
            int idx = k * 64 + lane;
            float4 w = W4[idx], v = x4[idx];
            s += w.x * v.x + w.y * v.y + w.z * v.z + w.w * v.w;
        }
        s = wave_reduce_sum(s);
        if (lane == 0) ws[WS_GATES + r] = s + ws[WS_HH + r];
    }
    grid.sync();

    // ---- Phase D: LSTM cell (block 0); blocks 512+ prefetch out_W [8MB,24MB) ----
    if (bid == 0) {
        const float* g = ws + WS_GATES;
        for (int e = t; e < HID; e += NT) {
            float i = 1.f / (1.f + expf(-g[e]));
            float f = 1.f / (1.f + expf(-g[HID + e]));
            float o = 1.f / (1.f + expf(-g[3 * HID + e]));
            float gv = tanhf(g[2 * HID + e]);
            float c = f * c0[e] + i * gv;
            float h = o * tanhf(c);
            out_c[e] = c;
            out_h[e] = h;
            ws[WS_H + e] = h;
        }
    } else if (bid >= 512) {
        const int p = bid - 512;                            // 0..511, 32KB each
        const float4* W4 = (const float4*)out_W;
        float acc = 0.f;
        for (int i = 0; i < 8; ++i) {
            float4 v = W4[524288 + (size_t)p * 2048 + i * 256 + t];
            acc += v.x + v.y + v.z + v.w;
        }
        asm volatile("" :: "v"(acc));
    }
    grid.sync();

    // ---- Phase E: logits + fused per-block online-LSE partials ----
    {
        const float4* h4 = (const float4*)(ws + WS_H);
        float4 hv[4];
        #pragma unroll
        for (int k = 0; k < 4; ++k) hv[k] = h4[k * 64 + lane];
        const int gid = bid * 4 + wid;                      // 0..4095
        float m = -1e30f, sacc = 0.f;
        for (int r = gid; r < VOC; r += 4096) {             // ~12 rows/wave
            const float4* W4 = (const float4*)(out_W + (size_t)r * HID);
            float s = 0.f;
            #pragma unroll
            for (int k = 0; k < 4; ++k) {
                float4 w = W4[k * 64 + lane];
                s += w.x * hv[k].x + w.y * hv[k].y + w.z * hv[k].z + w.w * hv[k].w;
            }
            s = wave_reduce_sum(s);
            if (lane == 0) {
                float v = s + out_b[r];
                out_logp[r] = v;
                if (v > m) { sacc = sacc * expf(m - v) + 1.f; m = v; }
                else       { sacc += expf(v - m); }
            }
        }
        if (lane == 0) { lds_m[wid] = m; lds_s[wid] = sacc; }
        __syncthreads();
        if (t == 0) {
            float M = lds_m[0], S = lds_s[0];
            for (int w = 1; w < 4; ++w) merge_ms(M, S, lds_m[w], lds_s[w]);
            ws[WS_PART + 2 * bid]     = M;
            ws[WS_PART + 2 * bid + 1] = S;
        }
    }
    grid.sync();

    // ---- Phase F: redundant LSE merge (11KB from L2) + subtract ----
    {
        float m = -1e30f, s = 0.f;
        for (int p = t; p < NB; p += NT)
            merge_ms(m, s, ws[WS_PART + 2 * p], ws[WS_PART + 2 * p + 1]);
        for (int off = 32; off > 0; off >>= 1) {
            float m2 = __shfl_xor(m, off, 64);
            float s2 = __shfl_xor(s, off, 64);
            merge_ms(m, s, m2, s2);
        }
        if (lane == 0) { lds_m[wid] = m; lds_s[wid] = s; }
        __syncthreads();
        if (t == 0) {
            float M = lds_m[0], S = lds_s[0];
            for (int w = 1; w < 4; ++w) merge_ms(M, S, lds_m[w], lds_s[w]);
            lds_bcast = M + logf(S);
        }
        __syncthreads();
        const float lse = lds_bcast;
        const int i = bid * NT + t;
        if (i < VOC) out_logp[i] -= lse;
    }
}

// ================= fallback chain (round-0 known-good kernels) =================
__global__ __launch_bounds__(256) void k1_embed_attn(
    const int* __restrict__ tok_p, const float* __restrict__ h0,
    const float* __restrict__ enc, const float* __restrict__ emb,
    const float* __restrict__ attn_W, const float* __restrict__ attn_b,
    float* __restrict__ ws_xin, float* __restrict__ out_attnw)
{
    __shared__ float lds_logits[MLEN];
    __shared__ float lds_w[MLEN];
    const int t = threadIdx.x;
    const int wid = t >> 6, lane = t & 63;
    const int tok = tok_p[0];
    const float4* emb4 = (const float4*)(emb + (size_t)tok * HID);
    const float4* h04  = (const float4*)h0;
    const float4* aW4  = (const float4*)attn_W;
    for (int l = wid; l < MLEN; l += 4) {
        float s = 0.f;
        for (int k = 0; k < 8; ++k) {
            int idx = k * 64 + lane;
            float4 v = (idx < 256) ? emb4[idx] : h04[idx - 256];
            float4 w = aW4[l * 512 + idx];
            s += v.x * w.x + v.y * w.y + v.z * w.z + v.w * w.w;
        }
        s = wave_reduce_sum(s);
        if (lane == 0) lds_logits[l] = s + attn_b[l];
    }
    __syncthreads();
    if (t == 0) {
        float m = -1e30f;
        for (int l = 0; l < MLEN; ++l) m = fmaxf(m, lds_logits[l]);
        float ssum = 0.f;
        for (int l = 0; l < MLEN; ++l) { float e = expf(lds_logits[l] - m); lds_w[l] = e; ssum += e; }
        float inv = 1.f / ssum;
        for (int l = 0; l < MLEN; ++l) { lds_w[l] *= inv; out_attnw[l] = lds_w[l]; }
    }
    __syncthreads();
    const float4* enc4 = (const float4*)enc;
    float4 e = emb4[t];
    float4 acc = make_float4(0.f, 0.f, 0.f, 0.f);
    for (int l = 0; l < MLEN; ++l) {
        float wl = lds_w[l];
        float4 v = enc4[l * 256 + t];
        acc.x += wl * v.x; acc.y += wl * v.y; acc.z += wl * v.z; acc.w += wl * v.w;
    }
    float4* xin4 = (float4*)ws_xin;
    xin4[t] = e;
    xin4[256 + t] = acc;
}

__global__ __launch_bounds__(256) void k2_comb_fb(
    const float* __restrict__ ws_xin, const float* __restrict__ comb_W,
    const float* __restrict__ comb_b, float* __restrict__ ws_x)
{
    const int wid = threadIdx.x >> 6, lane = threadIdx.x & 63;
    const int row = blockIdx.x * 4 + wid;
    const float4* W4 = (const float4*)(comb_W + (size_t)row * 2048);
    const float4* v4 = (const float4*)ws_xin;
    float s = 0.f;
    for (int k = 0; k < 8; ++k) {
        int idx = k * 64 + lane;
        float4 w = W4[idx], v = v4[idx];
        s += w.x * v.x + w.y * v.y + w.z * v.z + w.w * v.w;
    }
    s = wave_reduce_sum(s);
    if (lane == 0) ws_x[row] = fmaxf(s + comb_b[row], 0.f);
}

__global__ __launch_bounds__(256) void k3_gates_fb(
    const float* __restrict__ ws_x, const float* __restrict__ h0,
    const float* __restrict__ W_ih, const float* __restrict__ W_hh,
    const float* __restrict__ b_ih, const float* __restrict__ b_hh,
    float* __restrict__ ws_gates)
{
    const int wid = threadIdx.x >> 6, lane = threadIdx.x & 63;
    const int row = blockIdx.x * 4 + wid;
    const float4* Wi4 = (const float4*)(W_ih + (size_t)row * HID);
    const float4* Wh4 = (const float4*)(W_hh + (size_t)row * HID);
    const float4* x4  = (const float4*)ws_x;
    const float4* h4  = (const float4*)h0;
    float s = 0.f;
    for (int k = 0; k < 4; ++k) {
        int idx = k * 64 + lane;
        float4 wi = Wi4[idx], xv = x4[idx];
        float4 wh = Wh4[idx], hv = h4[idx];
        s += wi.x * xv.x + wi.y * xv.y + wi.z * xv.z + wi.w * xv.w;
        s += wh.x * hv.x + wh.y * hv.y + wh.z * hv.z + wh.w * hv.w;
    }
    s = wave_reduce_sum(s);
    if (lane == 0) ws_gates[row] = s + b_ih[row] + b_hh[row];
}

__global__ __launch_bounds__(1024) void k4_lstm_fb(
    const float* __restrict__ ws_gates, const float* __restrict__ c0,
    float* __restrict__ out_h, float* __restrict__ out_c, float* __restrict__ ws_h)
{
    const int t = threadIdx.x;
    float i = 1.f / (1.f + expf(-ws_gates[t]));
    float f = 1.f / (1.f + expf(-ws_gates[HID + t]));
    float o = 1.f / (1.f + expf(-ws_gates[3 * HID + t]));
    float g = tanhf(ws_gates[2 * HID + t]);
    float c = f * c0[t] + i * g;
    float h = o * tanhf(c);
    out_c[t] = c; out_h[t] = h; ws_h[t] = h;
}

__global__ __launch_bounds__(256) void k5_logits_fb(
    const float* __restrict__ ws_h, const float* __restrict__ out_W,
    const float* __restrict__ out_b, float* __restrict__ out_logp)
{
    const int wid = threadIdx.x >> 6, lane = threadIdx.x & 63;
    const int row = blockIdx.x * 4 + wid;
    if (row >= VOC) return;
    const float4* W4 = (const float4*)(out_W + (size_t)row * HID);
    const float4* h4 = (const float4*)ws_h;
    float s = 0.f;
    for (int k = 0; k < 4; ++k) {
        int idx = k * 64 + lane;
        float4 w = W4[idx], h = h4[idx];
        s += w.x * h.x + w.y * h.y + w.z * h.z + w.w * h.w;
    }
    s = wave_reduce_sum(s);
    if (lane == 0) out_logp[row] = s + out_b[row];
}

__global__ __launch_bounds__(1024) void k6_lse_fb(
    const float* __restrict__ logits, float* __restrict__ ws_lse)
{
    __shared__ float red[16];
    __shared__ float red2[16];
    const int t = threadIdx.x;
    const int wid = t >> 6, lane = t & 63;
    float m = -1e30f;
    for (int i = t; i < VOC; i += 1024) m = fmaxf(m, logits[i]);
    for (int off = 32; off > 0; off >>= 1) m = fmaxf(m, __shfl_xor(m, off, 64));
    if (lane == 0) red[wid] = m;
    __syncthreads();
    if (t == 0) {
        float mm = red[0];
        for (int w = 1; w < 16; ++w) mm = fmaxf(mm, red[w]);
        red[0] = mm;
    }
    __syncthreads();
    m = red[0];
    float s = 0.f;
    for (int i = t; i < VOC; i += 1024) s += expf(logits[i] - m);
    s = wave_reduce_sum(s);
    if (lane == 0) red2[wid] = s;
    __syncthreads();
    if (t == 0) {
        float ss = 0.f;
        for (int w = 0; w < 16; ++w) ss += red2[w];
        ws_lse[0] = m + logf(ss);
    }
}

__global__ __launch_bounds__(256) void k7_sub_fb(
    float* __restrict__ out_logp, const float* __restrict__ ws_lse)
{
    const int i = blockIdx.x * 256 + threadIdx.x;
    if (i < VOC) out_logp[i] -= ws_lse[0];
}

extern "C" void kernel_launch(void* const* d_in, const int* in_sizes, int n_in,
                              void* d_out, int out_size, void* d_ws, size_t ws_size,
                              hipStream_t stream) {
    const int*   tok      = (const int*)d_in[0];
    const float* h_hidden = (const float*)d_in[1];
    const float* c_hidden = (const float*)d_in[2];
    const float* enc      = (const float*)d_in[3];
    const float* emb      = (const float*)d_in[4];
    const float* attn_W   = (const float*)d_in[5];
    const float* attn_b   = (const float*)d_in[6];
    const float* comb_W   = (const float*)d_in[7];
    const float* comb_b   = (const float*)d_in[8];
    const float* W_ih     = (const float*)d_in[9];
    const float* W_hh     = (const float*)d_in[10];
    const float* b_ih     = (const float*)d_in[11];
    const float* b_hh     = (const float*)d_in[12];
    const float* out_W    = (const float*)d_in[13];
    const float* out_b    = (const float*)d_in[14];

    float* out       = (float*)d_out;
    float* out_logp  = out;                       // [50257]
    float* out_h     = out + VOC;                 // [1024]
    float* out_c     = out + VOC + HID;           // [1024]
    float* out_attnw = out + VOC + 2 * HID;       // [12]

    float* ws = (float*)d_ws;

    void* args[] = {
        (void*)&tok, (void*)&h_hidden, (void*)&enc, (void*)&emb,
        (void*)&attn_W, (void*)&attn_b, (void*)&comb_W, (void*)&comb_b,
        (void*)&W_ih, (void*)&W_hh, (void*)&b_ih, (void*)&b_hh,
        (void*)&out_W, (void*)&out_b, (void*)&c_hidden, (void*)&ws,
        (void*)&out_logp, (void*)&out_h, (void*)&out_c, (void*)&out_attnw
    };
    hipError_t err = hipLaunchCooperativeKernel((const void*)mega, dim3(NB), dim3(NT),
                                                args, 0, stream);
    if (err != hipSuccess) {
        // fallback: known-good multi-kernel chain (round-0 layout)
        float* ws_xin   = ws;            // 2048
        float* ws_x     = ws + 2048;     // 1024
        float* ws_gates = ws + 3072;     // 4096
        float* ws_h     = ws + 7168;     // 1024
        float* ws_lse   = ws + 8192;     // 1
        k1_embed_attn<<<1, 256, 0, stream>>>(tok, h_hidden, enc, emb, attn_W, attn_b,
                                             ws_xin, out_attnw);
        k2_comb_fb<<<HID / 4, 256, 0, stream>>>(ws_xin, comb_W, comb_b, ws_x);
        k3_gates_fb<<<4 * HID / 4, 256, 0, stream>>>(ws_x, h_hidden, W_ih, W_hh,
                                                     b_ih, b_hh, ws_gates);
        k4_lstm_fb<<<1, 1024, 0, stream>>>(ws_gates, c_hidden, out_h, out_c, ws_h);
        k5_logits_fb<<<(VOC + 3) / 4, 256, 0, stream>>>(ws_h, out_W, out_b, out_logp);
        k6_lse_fb<<<1, 1024, 0, stream>>>(out_logp, ws_lse);
        k7_sub_fb<<<(VOC + 255) / 256, 256, 0, stream>>>(out_logp, ws_lse);
    }
}

// Round 3
// 427.981 us; speedup vs baseline: 2.2818x; 2.2818x over previous
//
#include <hip/hip_runtime.h>
#include <math.h>

#define HID 1024
#define VOC 50257
#define MLEN 12

#define K1_DOT_BLOCKS 1280     // 5120 waves: 1024 pcomb rows + 4096 hh rows
#define K5_BLOCKS ((VOC + 3) / 4)   // 12565

// ws layout (floats)
#define WS_ATTN   0      // [1024] attn_applied
#define WS_X      1024   // [1024] relu output
#define WS_PCOMB  2048   // [1024] comb_W[:, :H] @ embedded + comb_b
#define WS_HH     3072   // [4096] W_hh @ h0 + b_ih + b_hh
#define WS_GATES  7168   // [4096]
#define WS_H      11264  // [1024] h_new (16B aligned copy)
#define WS_LSE    12288  // [1]
#define WS_PART   12290  // [2 * K5_BLOCKS] per-block (m, s) LSE partials

__device__ __forceinline__ float wave_reduce_sum(float v) {
    for (int off = 32; off > 0; off >>= 1)
        v += __shfl_down(v, off, 64);
    return v;
}

__device__ __forceinline__ void merge_ms(float& m, float& s, float m2, float s2) {
    float M = fmaxf(m, m2);
    s = s * expf(m - M) + s2 * expf(m2 - M);
    m = M;
}

// K1: block 0 = attention softmax + attn_applied; blocks 1..1280 = input-only
// GEMV halves (comb first-half on embedded, W_hh@h0 + biases). No fences, no
// prefetch — hoisted work rides under block 0's latency-bound attention.
__global__ __launch_bounds__(256) void k1_embed_attn(
    const int* __restrict__ tok_p, const float* __restrict__ h0,
    const float* __restrict__ enc, const float* __restrict__ emb,
    const float* __restrict__ attn_W, const float* __restrict__ attn_b,
    const float* __restrict__ comb_W, const float* __restrict__ comb_b,
    const float* __restrict__ W_hh, const float* __restrict__ b_ih,
    const float* __restrict__ b_hh,
    float* __restrict__ ws, float* __restrict__ out_attnw)
{
    const int t = threadIdx.x;
    const int wid = t >> 6, lane = t & 63;
    const int bid = blockIdx.x;
    const int tok = tok_p[0];  // int64 little-endian low word (tok < 50257)
    const float4* emb4 = (const float4*)(emb + (size_t)tok * HID);
    const float4* h04  = (const float4*)h0;

    if (bid == 0) {
        __shared__ float lds_logits[MLEN];
        __shared__ float lds_w[MLEN];
        const float4* aW4 = (const float4*)attn_W;
        for (int l = wid; l < MLEN; l += 4) {
            float s = 0.f;
            for (int k = 0; k < 8; ++k) {
                int idx = k * 64 + lane;                  // 0..511 float4s of [emb,h0]
                float4 v = (idx < 256) ? emb4[idx] : h04[idx - 256];
                float4 w = aW4[l * 512 + idx];
                s += v.x * w.x + v.y * w.y + v.z * w.z + v.w * w.w;
            }
            s = wave_reduce_sum(s);
            if (lane == 0) lds_logits[l] = s + attn_b[l];
        }
        __syncthreads();
        if (t == 0) {
            float m = -1e30f;
            for (int l = 0; l < MLEN; ++l) m = fmaxf(m, lds_logits[l]);
            float ssum = 0.f;
            for (int l = 0; l < MLEN; ++l) { float e = expf(lds_logits[l] - m); lds_w[l] = e; ssum += e; }
            float inv = 1.f / ssum;
            for (int l = 0; l < MLEN; ++l) { lds_w[l] *= inv; out_attnw[l] = lds_w[l]; }
        }
        __syncthreads();
        const float4* enc4 = (const float4*)enc;
        float4 acc = make_float4(0.f, 0.f, 0.f, 0.f);
        for (int l = 0; l < MLEN; ++l) {
            float wl = lds_w[l];
            float4 v = enc4[l * 256 + t];
            acc.x += wl * v.x; acc.y += wl * v.y; acc.z += wl * v.z; acc.w += wl * v.w;
        }
        ((float4*)(ws + WS_ATTN))[t] = acc;
    } else {
        const int task = (bid - 1) * 4 + wid;             // 0..5119
        float s = 0.f;
        if (task < 1024) {
            // pcomb[task] = comb_W[task, :H] @ embedded + comb_b[task]
            const float4* W4 = (const float4*)(comb_W + (size_t)task * 2 * HID);
            for (int k = 0; k < 4; ++k) {
                int idx = k * 64 + lane;
                float4 w = W4[idx], v = emb4[idx];
                s += w.x * v.x + w.y * v.y + w.z * v.z + w.w * v.w;
            }
            s = wave_reduce_sum(s);
            if (lane == 0) ws[WS_PCOMB + task] = s + comb_b[task];
        } else {
            // hh[r] = W_hh[r,:] @ h0 + b_ih[r] + b_hh[r]
            const int r = task - 1024;                    // 0..4095
            const float4* W4 = (const float4*)(W_hh + (size_t)r * HID);
            for (int k = 0; k < 4; ++k) {
                int idx = k * 64 + lane;
                float4 w = W4[idx], v = h04[idx];
                s += w.x * v.x + w.y * v.y + w.z * v.z + w.w * v.w;
            }
            s = wave_reduce_sum(s);
            if (lane == 0) ws[WS_HH + r] = s + b_ih[r] + b_hh[r];
        }
    }
}

// K2: x[r] = relu(pcomb[r] + comb_W[r, H:] @ attn_applied); dot length 1024
__global__ __launch_bounds__(256) void k2_comb(
    const float* __restrict__ comb_W, float* __restrict__ ws)
{
    const int wid = threadIdx.x >> 6, lane = threadIdx.x & 63;
    const int row = blockIdx.x * 4 + wid;                 // 0..1023
    const float4* W4 = (const float4*)(comb_W + (size_t)row * 2 * HID + HID);
    const float4* v4 = (const float4*)(ws + WS_ATTN);
    float s = 0.f;
    for (int k = 0; k < 4; ++k) {
        int idx = k * 64 + lane;
        float4 w = W4[idx], v = v4[idx];
        s += w.x * v.x + w.y * v.y + w.z * v.z + w.w * v.w;
    }
    s = wave_reduce_sum(s);
    if (lane == 0) ws[WS_X + row] = fmaxf(s + ws[WS_PCOMB + row], 0.f);
}

// K3: gates[r] = hh[r] + W_ih[r,:] @ x; dot length 1024
__global__ __launch_bounds__(256) void k3_gates(
    const float* __restrict__ W_ih, float* __restrict__ ws)
{
    const int wid = threadIdx.x >> 6, lane = threadIdx.x & 63;
    const int row = blockIdx.x * 4 + wid;                 // 0..4095
    const float4* W4 = (const float4*)(W_ih + (size_t)row * HID);
    const float4* x4 = (const float4*)(ws + WS_X);
    float s = 0.f;
    for (int k = 0; k < 4; ++k) {
        int idx = k * 64 + lane;
        float4 w = W4[idx], v = x4[idx];
        s += w.x * v.x + w.y * v.y + w.z * v.z + w.w * v.w;
    }
    s = wave_reduce_sum(s);
    if (lane == 0) ws[WS_GATES + row] = s + ws[WS_HH + row];
}

// K4: LSTM cell elementwise (PyTorch gate order i,f,g,o)
__global__ __launch_bounds__(1024) void k4_lstm(
    const float* __restrict__ c0, float* __restrict__ ws,
    float* __restrict__ out_h, float* __restrict__ out_c)
{
    const int t = threadIdx.x;
    const float* g = ws + WS_GATES;
    float i = 1.f / (1.f + expf(-g[t]));
    float f = 1.f / (1.f + expf(-g[HID + t]));
    float o = 1.f / (1.f + expf(-g[3 * HID + t]));
    float gv = tanhf(g[2 * HID + t]);
    float c = f * c0[t] + i * gv;
    float h = o * tanhf(c);
    out_c[t] = c;
    out_h[t] = h;
    ws[WS_H + t] = h;   // 16B-aligned copy for K5's float4 reads
}

// K5: logits = out_W @ h + out_b; wave per row; fused per-block (m,s) LSE partial
__global__ __launch_bounds__(256) void k5_logits(
    const float* __restrict__ out_W, const float* __restrict__ out_b,
    float* __restrict__ ws, float* __restrict__ out_logp)
{
    __shared__ float lds_logit[4];
    const int wid = threadIdx.x >> 6, lane = threadIdx.x & 63;
    const int row = blockIdx.x * 4 + wid;
    float logit = -1e30f;
    if (row < VOC) {
        const float4* W4 = (const float4*)(out_W + (size_t)row * HID);
        const float4* h4 = (const float4*)(ws + WS_H);
        float s = 0.f;
        for (int k = 0; k < 4; ++k) {
            int idx = k * 64 + lane;
            float4 w = W4[idx], h = h4[idx];
            s += w.x * h.x + w.y * h.y + w.z * h.z + w.w * h.w;
        }
        s = wave_reduce_sum(s);
        if (lane == 0) {
            logit = s + out_b[row];
            out_logp[row] = logit;
        }
    }
    if (lane == 0) lds_logit[wid] = logit;
    __syncthreads();
    if (threadIdx.x == 0) {
        float m = lds_logit[0];
        for (int w = 1; w < 4; ++w) m = fmaxf(m, lds_logit[w]);
        float s = 0.f;
        for (int w = 0; w < 4; ++w) s += expf(lds_logit[w] - m);   // exp(-inf-ish)=0 for pads
        ws[WS_PART + 2 * blockIdx.x]     = m;
        ws[WS_PART + 2 * blockIdx.x + 1] = s;
    }
}

// K6: merge 12565 (m,s) partials -> lse (one block; ~100 KB from L2)
__global__ __launch_bounds__(1024) void k6_lse(float* __restrict__ ws)
{
    __shared__ float red_m[16], red_s[16];
    const int t = threadIdx.x;
    const int wid = t >> 6, lane = t & 63;
    float m = -1e30f, s = 0.f;
    for (int p = t; p < K5_BLOCKS; p += 1024)
        merge_ms(m, s, ws[WS_PART + 2 * p], ws[WS_PART + 2 * p + 1]);
    for (int off = 32; off > 0; off >>= 1) {
        float m2 = __shfl_xor(m, off, 64);
        float s2 = __shfl_xor(s, off, 64);
        merge_ms(m, s, m2, s2);
    }
    if (lane == 0) { red_m[wid] = m; red_s[wid] = s; }
    __syncthreads();
    if (t == 0) {
        float M = red_m[0], S = red_s[0];
        for (int w = 1; w < 16; ++w) merge_ms(M, S, red_m[w], red_s[w]);
        ws[WS_LSE] = M + logf(S);
    }
}

// K7: logp = logits - lse (in place)
__global__ __launch_bounds__(256) void k7_sub(
    float* __restrict__ out_logp, const float* __restrict__ ws)
{
    const int i = blockIdx.x * 256 + threadIdx.x;
    if (i < VOC) out_logp[i] -= ws[WS_LSE];
}

extern "C" void kernel_launch(void* const* d_in, const int* in_sizes, int n_in,
                              void* d_out, int out_size, void* d_ws, size_t ws_size,
                              hipStream_t stream) {
    const int*   tok      = (const int*)d_in[0];
    const float* h_hidden = (const float*)d_in[1];
    const float* c_hidden = (const float*)d_in[2];
    const float* enc      = (const float*)d_in[3];
    const float* emb      = (const float*)d_in[4];
    const float* attn_W   = (const float*)d_in[5];
    const float* attn_b   = (const float*)d_in[6];
    const float* comb_W   = (const float*)d_in[7];
    const float* comb_b   = (const float*)d_in[8];
    const float* W_ih     = (const float*)d_in[9];
    const float* W_hh     = (const float*)d_in[10];
    const float* b_ih     = (const float*)d_in[11];
    const float* b_hh     = (const float*)d_in[12];
    const float* out_W    = (const float*)d_in[13];
    const float* out_b    = (const float*)d_in[14];

    float* out       = (float*)d_out;
    float* out_logp  = out;                       // [50257]
    float* out_h     = out + VOC;                 // [1024]
    float* out_c     = out + VOC + HID;           // [1024]
    float* out_attnw = out + VOC + 2 * HID;       // [12]

    float* ws = (float*)d_ws;

    k1_embed_attn<<<1 + K1_DOT_BLOCKS, 256, 0, stream>>>(
        tok, h_hidden, enc, emb, attn_W, attn_b, comb_W, comb_b,
        W_hh, b_ih, b_hh, ws, out_attnw);
    k2_comb<<<HID / 4, 256, 0, stream>>>(comb_W, ws);
    k3_gates<<<4 * HID / 4, 256, 0, stream>>>(W_ih, ws);
    k4_lstm<<<1, 1024, 0, stream>>>(c_hidden, ws, out_h, out_c);
    k5_logits<<<K5_BLOCKS, 256, 0, stream>>>(out_W, out_b, ws, out_logp);
    k6_lse<<<1, 1024, 0, stream>>>(ws);
    k7_sub<<<(VOC + 255) / 256, 256, 0, stream>>>(out_logp, ws);
}

// Round 4
// 427.490 us; speedup vs baseline: 2.2845x; 1.0011x over previous
//
#include <hip/hip_runtime.h>
#include <math.h>

#define HID 1024
#define VOC 50257
#define MLEN 12

#define K1_DOT_BLOCKS 1280          // 5120 waves: 1024 pcomb rows + 4096 hh rows
#define K5_BLOCKS ((VOC + 7) / 8)   // 6283, 2 rows per wave, 8 rows per block
#define NPART K5_BLOCKS

// ws layout (floats)
#define WS_ATTN   0      // [1024] attn_applied
#define WS_X      1024   // [1024] relu output
#define WS_PCOMB  2048   // [1024] comb_W[:, :H] @ embedded + comb_b
#define WS_HH     3072   // [4096] W_hh @ h0 + b_ih + b_hh
#define WS_GATES  7168   // [4096]
#define WS_H      11264  // [1024] h_new (16B aligned copy)
#define WS_PART   12288  // [2 * NPART] per-block (m, s) LSE partials

__device__ __forceinline__ float wave_reduce_sum(float v) {
    for (int off = 32; off > 0; off >>= 1)
        v += __shfl_down(v, off, 64);
    return v;
}

__device__ __forceinline__ void merge_ms(float& m, float& s, float m2, float s2) {
    float M = fmaxf(m, m2);
    s = s * expf(m - M) + s2 * expf(m2 - M);
    m = M;
}

// K1: block 0 = attention softmax + attn_applied; blocks 1..1280 = input-only
// GEMV halves (comb first-half on embedded, W_hh@h0 + biases).
__global__ __launch_bounds__(256) void k1_embed_attn(
    const int* __restrict__ tok_p, const float* __restrict__ h0,
    const float* __restrict__ enc, const float* __restrict__ emb,
    const float* __restrict__ attn_W, const float* __restrict__ attn_b,
    const float* __restrict__ comb_W, const float* __restrict__ comb_b,
    const float* __restrict__ W_hh, const float* __restrict__ b_ih,
    const float* __restrict__ b_hh,
    float* __restrict__ ws, float* __restrict__ out_attnw)
{
    const int t = threadIdx.x;
    const int wid = t >> 6, lane = t & 63;
    const int bid = blockIdx.x;
    const int tok = tok_p[0];  // int64 little-endian low word (tok < 50257)
    const float4* emb4 = (const float4*)(emb + (size_t)tok * HID);
    const float4* h04  = (const float4*)h0;

    if (bid == 0) {
        __shared__ float lds_logits[MLEN];
        __shared__ float lds_w[MLEN];
        const float4* aW4 = (const float4*)attn_W;
        for (int l = wid; l < MLEN; l += 4) {
            float s = 0.f;
            for (int k = 0; k < 8; ++k) {
                int idx = k * 64 + lane;                  // 0..511 float4s of [emb,h0]
                float4 v = (idx < 256) ? emb4[idx] : h04[idx - 256];
                float4 w = aW4[l * 512 + idx];
                s += v.x * w.x + v.y * w.y + v.z * w.z + v.w * w.w;
            }
            s = wave_reduce_sum(s);
            if (lane == 0) lds_logits[l] = s + attn_b[l];
        }
        __syncthreads();
        if (t == 0) {
            float m = -1e30f;
            for (int l = 0; l < MLEN; ++l) m = fmaxf(m, lds_logits[l]);
            float ssum = 0.f;
            for (int l = 0; l < MLEN; ++l) { float e = expf(lds_logits[l] - m); lds_w[l] = e; ssum += e; }
            float inv = 1.f / ssum;
            for (int l = 0; l < MLEN; ++l) { lds_w[l] *= inv; out_attnw[l] = lds_w[l]; }
        }
        __syncthreads();
        const float4* enc4 = (const float4*)enc;
        float4 acc = make_float4(0.f, 0.f, 0.f, 0.f);
        for (int l = 0; l < MLEN; ++l) {
            float wl = lds_w[l];
            float4 v = enc4[l * 256 + t];
            acc.x += wl * v.x; acc.y += wl * v.y; acc.z += wl * v.z; acc.w += wl * v.w;
        }
        ((float4*)(ws + WS_ATTN))[t] = acc;
    } else {
        const int task = (bid - 1) * 4 + wid;             // 0..5119
        float s = 0.f;
        if (task < 1024) {
            // pcomb[task] = comb_W[task, :H] @ embedded + comb_b[task]
            const float4* W4 = (const float4*)(comb_W + (size_t)task * 2 * HID);
            for (int k = 0; k < 4; ++k) {
                int idx = k * 64 + lane;
                float4 w = W4[idx], v = emb4[idx];
                s += w.x * v.x + w.y * v.y + w.z * v.z + w.w * v.w;
            }
            s = wave_reduce_sum(s);
            if (lane == 0) ws[WS_PCOMB + task] = s + comb_b[task];
        } else {
            // hh[r] = W_hh[r,:] @ h0 + b_ih[r] + b_hh[r]
            const int r = task - 1024;                    // 0..4095
            const float4* W4 = (const float4*)(W_hh + (size_t)r * HID);
            for (int k = 0; k < 4; ++k) {
                int idx = k * 64 + lane;
                float4 w = W4[idx], v = h04[idx];
                s += w.x * v.x + w.y * v.y + w.z * v.z + w.w * v.w;
            }
            s = wave_reduce_sum(s);
            if (lane == 0) ws[WS_HH + r] = s + b_ih[r] + b_hh[r];
        }
    }
}

// K2: x[r] = relu(pcomb[r] + comb_W[r, H:] @ attn_applied); dot length 1024
__global__ __launch_bounds__(256) void k2_comb(
    const float* __restrict__ comb_W, float* __restrict__ ws)
{
    const int wid = threadIdx.x >> 6, lane = threadIdx.x & 63;
    const int row = blockIdx.x * 4 + wid;                 // 0..1023
    const float4* W4 = (const float4*)(comb_W + (size_t)row * 2 * HID + HID);
    const float4* v4 = (const float4*)(ws + WS_ATTN);
    float s = 0.f;
    for (int k = 0; k < 4; ++k) {
        int idx = k * 64 + lane;
        float4 w = W4[idx], v = v4[idx];
        s += w.x * v.x + w.y * v.y + w.z * v.z + w.w * v.w;
    }
    s = wave_reduce_sum(s);
    if (lane == 0) ws[WS_X + row] = fmaxf(s + ws[WS_PCOMB + row], 0.f);
}

// K3: gates[r] = hh[r] + W_ih[r,:] @ x; dot length 1024
__global__ __launch_bounds__(256) void k3_gates(
    const float* __restrict__ W_ih, float* __restrict__ ws)
{
    const int wid = threadIdx.x >> 6, lane = threadIdx.x & 63;
    const int row = blockIdx.x * 4 + wid;                 // 0..4095
    const float4* W4 = (const float4*)(W_ih + (size_t)row * HID);
    const float4* x4 = (const float4*)(ws + WS_X);
    float s = 0.f;
    for (int k = 0; k < 4; ++k) {
        int idx = k * 64 + lane;
        float4 w = W4[idx], v = x4[idx];
        s += w.x * v.x + w.y * v.y + w.z * v.z + w.w * v.w;
    }
    s = wave_reduce_sum(s);
    if (lane == 0) ws[WS_GATES + row] = s + ws[WS_HH + row];
}

// K4: LSTM cell elementwise (PyTorch gate order i,f,g,o)
__global__ __launch_bounds__(1024) void k4_lstm(
    const float* __restrict__ c0, float* __restrict__ ws,
    float* __restrict__ out_h, float* __restrict__ out_c)
{
    const int t = threadIdx.x;
    const float* g = ws + WS_GATES;
    float i = 1.f / (1.f + expf(-g[t]));
    float f = 1.f / (1.f + expf(-g[HID + t]));
    float o = 1.f / (1.f + expf(-g[3 * HID + t]));
    float gv = tanhf(g[2 * HID + t]);
    float c = f * c0[t] + i * gv;
    float h = o * tanhf(c);
    out_c[t] = c;
    out_h[t] = h;
    ws[WS_H + t] = h;   // 16B-aligned copy for K5's float4 reads
}

// K5: logits = out_W @ h + out_b; 2 rows per wave (ILP on the BW-bound stream);
// fused per-block (m,s) LSE partial over this block's 8 rows.
__global__ __launch_bounds__(256) void k5_logits(
    const float* __restrict__ out_W, const float* __restrict__ out_b,
    float* __restrict__ ws, float* __restrict__ out_logp)
{
    __shared__ float lds_logit[8];
    const int wid = threadIdx.x >> 6, lane = threadIdx.x & 63;
    const int r0 = blockIdx.x * 8 + wid * 2;              // 2 rows per wave

    const float4* h4 = (const float4*)(ws + WS_H);
    float4 hv[4];
    #pragma unroll
    for (int k = 0; k < 4; ++k) hv[k] = h4[k * 64 + lane];

    float s0 = 0.f, s1 = 0.f;
    if (r0 + 1 < VOC) {
        const float4* W0 = (const float4*)(out_W + (size_t)r0 * HID);
        const float4* W1 = (const float4*)(out_W + (size_t)(r0 + 1) * HID);
        #pragma unroll
        for (int k = 0; k < 4; ++k) {
            float4 w0 = W0[k * 64 + lane];
            float4 w1 = W1[k * 64 + lane];
            s0 += w0.x * hv[k].x + w0.y * hv[k].y + w0.z * hv[k].z + w0.w * hv[k].w;
            s1 += w1.x * hv[k].x + w1.y * hv[k].y + w1.z * hv[k].z + w1.w * hv[k].w;
        }
    } else if (r0 < VOC) {
        const float4* W0 = (const float4*)(out_W + (size_t)r0 * HID);
        #pragma unroll
        for (int k = 0; k < 4; ++k) {
            float4 w0 = W0[k * 64 + lane];
            s0 += w0.x * hv[k].x + w0.y * hv[k].y + w0.z * hv[k].z + w0.w * hv[k].w;
        }
    }
    for (int off = 32; off > 0; off >>= 1) {
        s0 += __shfl_down(s0, off, 64);
        s1 += __shfl_down(s1, off, 64);
    }
    if (lane == 0) {
        float l0 = (r0     < VOC) ? s0 + out_b[r0]     : -1e30f;
        float l1 = (r0 + 1 < VOC) ? s1 + out_b[r0 + 1] : -1e30f;
        if (r0     < VOC) out_logp[r0]     = l0;
        if (r0 + 1 < VOC) out_logp[r0 + 1] = l1;
        lds_logit[wid * 2]     = l0;
        lds_logit[wid * 2 + 1] = l1;
    }
    __syncthreads();
    if (threadIdx.x == 0) {
        float m = lds_logit[0];
        for (int j = 1; j < 8; ++j) m = fmaxf(m, lds_logit[j]);
        float s = 0.f;
        for (int j = 0; j < 8; ++j) s += expf(lds_logit[j] - m);   // pads contribute 0
        ws[WS_PART + 2 * blockIdx.x]     = m;
        ws[WS_PART + 2 * blockIdx.x + 1] = s;
    }
}

// K7: each block redundantly merges the 6283 (m,s) partials (50 KB, L2-hit),
// then subtracts the LSE from its own 1024 logits. Replaces K6 + K7.
__global__ __launch_bounds__(1024) void k7_lse_sub(
    float* __restrict__ out_logp, const float* __restrict__ ws)
{
    __shared__ float red_m[16], red_s[16];
    __shared__ float bcast;
    const int t = threadIdx.x;
    const int wid = t >> 6, lane = t & 63;
    float m = -1e30f, s = 0.f;
    for (int p = t; p < NPART; p += 1024)
        merge_ms(m, s, ws[WS_PART + 2 * p], ws[WS_PART + 2 * p + 1]);
    for (int off = 32; off > 0; off >>= 1) {
        float m2 = __shfl_xor(m, off, 64);
        float s2 = __shfl_xor(s, off, 64);
        merge_ms(m, s, m2, s2);
    }
    if (lane == 0) { red_m[wid] = m; red_s[wid] = s; }
    __syncthreads();
    if (t == 0) {
        float M = red_m[0], S = red_s[0];
        for (int w = 1; w < 16; ++w) merge_ms(M, S, red_m[w], red_s[w]);
        bcast = M + logf(S);
    }
    __syncthreads();
    const float lse = bcast;
    const int i = blockIdx.x * 1024 + t;
    if (i < VOC) out_logp[i] -= lse;
}

extern "C" void kernel_launch(void* const* d_in, const int* in_sizes, int n_in,
                              void* d_out, int out_size, void* d_ws, size_t ws_size,
                              hipStream_t stream) {
    const int*   tok      = (const int*)d_in[0];
    const float* h_hidden = (const float*)d_in[1];
    const float* c_hidden = (const float*)d_in[2];
    const float* enc      = (const float*)d_in[3];
    const float* emb      = (const float*)d_in[4];
    const float* attn_W   = (const float*)d_in[5];
    const float* attn_b   = (const float*)d_in[6];
    const float* comb_W   = (const float*)d_in[7];
    const float* comb_b   = (const float*)d_in[8];
    const float* W_ih     = (const float*)d_in[9];
    const float* W_hh     = (const float*)d_in[10];
    const float* b_ih     = (const float*)d_in[11];
    const float* b_hh     = (const float*)d_in[12];
    const float* out_W    = (const float*)d_in[13];
    const float* out_b    = (const float*)d_in[14];

    float* out       = (float*)d_out;
    float* out_logp  = out;                       // [50257]
    float* out_h     = out + VOC;                 // [1024]
    float* out_c     = out + VOC + HID;           // [1024]
    float* out_attnw = out + VOC + 2 * HID;       // [12]

    float* ws = (float*)d_ws;

    k1_embed_attn<<<1 + K1_DOT_BLOCKS, 256, 0, stream>>>(
        tok, h_hidden, enc, emb, attn_W, attn_b, comb_W, comb_b,
        W_hh, b_ih, b_hh, ws, out_attnw);
    k2_comb<<<HID / 4, 256, 0, stream>>>(comb_W, ws);
    k3_gates<<<4 * HID / 4, 256, 0, stream>>>(W_ih, ws);
    k4_lstm<<<1, 1024, 0, stream>>>(c_hidden, ws, out_h, out_c);
    k5_logits<<<K5_BLOCKS, 256, 0, stream>>>(out_W, out_b, ws, out_logp);
    k7_lse_sub<<<(VOC + 1023) / 1024, 1024, 0, stream>>>(out_logp, ws);
}